// Round 11
// baseline (437.038 us; speedup 1.0000x reference)
//
#include <hip/hip_runtime.h>
#include <math.h>

#define NBROWS 262144
#define WS_TOT 7808

// Folded weights in constant address space: uniform compile-time offsets ->
// compiler emits batched s_load (scalar pipe), zero VGPR/LDS/VALU cost.
__constant__ float cw[WS_TOT];

// ---------------- packed d_ws layout (floats) — R6/R9-proven ----------------
// P1 [0,1152):     36 pairs (u<=v) x 32: [Sss w0..15][Svv0 w0..15]
// C1 [1152,2176):  (vv*8+u)*16 + w
// A1 [2176,2624):  28 pairs (u<v) x 16
// P2 [2624,4800):  136 pairs (u<=v) x 16: [Sss w0..7][Svv0 w0..7]
// C2 [4800,6848):  (vv*16+u)*8 + w
// A2 [6848,7808):  120 pairs (u<v) x 8

__device__ __forceinline__ void pair_le(int p, int M, int& u, int& v) {
    u = 0; int cnt = M;
    while (p >= cnt) { p -= cnt; ++u; cnt = M - u; }
    v = u + p;
}
__device__ __forceinline__ void pair_lt(int p, int M, int& u, int& v) {
    u = 0; int cnt = M - 1;
    while (p >= cnt) { p -= cnt; ++u; cnt = M - 1 - u; }
    v = u + 1 + p;
}

__global__ __launch_bounds__(256) void prep_kernel(
    const float* __restrict__ w1_ss, const float* __restrict__ w1_vv0,
    const float* __restrict__ w1_sv, const float* __restrict__ w1_vs,
    const float* __restrict__ w1_vv1,
    const float* __restrict__ w2_ss, const float* __restrict__ w2_vv0,
    const float* __restrict__ w2_sv, const float* __restrict__ w2_vs,
    const float* __restrict__ w2_vv1,
    float* __restrict__ ws)
{
    const float inv3 = 0.5773502691896258f;
    const float inv6 = 0.4082482904638631f;
    int i = blockIdx.x * 256 + threadIdx.x;
    if (i >= WS_TOT) return;
    float val = 0.f;
    if (i < 1152) {                       // P1
        int p = i >> 5, r = i & 31;
        int which = r >> 4, w = r & 15;
        int u, v; pair_le(p, 8, u, v);
        const float c0 = 0.08838834764831845f;
        const float* src = which ? w1_vv0 : w1_ss;
        float cc = which ? c0 * inv3 : c0;
        val = (u == v) ? cc * src[(u*8+v)*16+w]
                       : cc * (src[(u*8+v)*16+w] + src[(v*8+u)*16+w]);
    } else if (i < 2176) {                // C1
        int r = i - 1152; int vv = r >> 7, rem = r & 127, u = rem >> 4, w = rem & 15;
        val = (0.125f * inv3) * (w1_sv[(u*8+vv)*16+w] + w1_vs[(vv*8+u)*16+w]);
    } else if (i < 2624) {                // A1
        int r = i - 2176; int p = r >> 4, w = r & 15;
        int u, v; pair_lt(p, 8, u, v);
        val = (0.125f * inv6) * (w1_vv1[(u*8+v)*16+w] - w1_vv1[(v*8+u)*16+w]);
    } else if (i < 4800) {                // P2
        int r = i - 2624; int p = r >> 4, rr = r & 15, which = rr >> 3, w = rr & 7;
        int u, v; pair_le(p, 16, u, v);
        const float c0 = 0.04419417382415922f;
        const float* src = which ? w2_vv0 : w2_ss;
        float cc = which ? c0 * inv3 : c0;
        val = (u == v) ? cc * src[(u*16+v)*8+w]
                       : cc * (src[(u*16+v)*8+w] + src[(v*16+u)*8+w]);
    } else if (i < 6848) {                // C2
        int r = i - 4800; int vv = r >> 7, rem = r & 127, u = rem >> 3, w = rem & 7;
        val = (0.0625f * inv3) * (w2_sv[(u*16+vv)*8+w] + w2_vs[(vv*16+u)*8+w]);
    } else {                              // A2
        int r = i - 6848; int p = r >> 3, w = r & 7;
        int u, v; pair_lt(p, 16, u, v);
        val = (0.0625f * inv6) * (w2_vv1[(u*16+v)*8+w] - w2_vv1[(v*16+u)*8+w]);
    }
    ws[i] = val;
}

// ---------------- layer 1: 8 -> 16, chunk of 8 outputs ----------------------
template<int W0>
__device__ __forceinline__ void l1_chunk(
    const float (&s)[8], const float (&v)[8][3],
    float (&ys)[16], float (&ox)[16], float (&oy)[16], float (&oz)[16])
{
#pragma unroll
    for (int w = 0; w < 8; ++w) { ys[W0+w]=0.f; ox[W0+w]=0.f; oy[W0+w]=0.f; oz[W0+w]=0.f; }
    {   // symmetric ss + vv0
        int p = 0;
#pragma unroll
        for (int u = 0; u < 8; ++u)
#pragma unroll
        for (int vv = u; vv < 8; ++vv) {
            float pp = s[u] * s[vv];
            float dd = v[u][0]*v[vv][0] + v[u][1]*v[vv][1] + v[u][2]*v[vv][2];
#pragma unroll
            for (int w = 0; w < 8; ++w)
                ys[W0+w] += pp * cw[p*32 + W0 + w] + dd * cw[p*32 + 16 + W0 + w];
            ++p;
        }
    }
    // combined sv+vs
#pragma unroll
    for (int vv = 0; vv < 8; ++vv) {
        float tw[8];
#pragma unroll
        for (int w = 0; w < 8; ++w) tw[w] = 0.f;
#pragma unroll
        for (int u = 0; u < 8; ++u) {
            float su = s[u];
#pragma unroll
            for (int w = 0; w < 8; ++w) tw[w] += su * cw[1152 + (vv*8+u)*16 + W0 + w];
        }
#pragma unroll
        for (int w = 0; w < 8; ++w) {
            ox[W0+w] += tw[w] * v[vv][0];
            oy[W0+w] += tw[w] * v[vv][1];
            oz[W0+w] += tw[w] * v[vv][2];
        }
    }
    {   // antisymmetric cross
        int p = 0;
#pragma unroll
        for (int u = 0; u < 8; ++u)
#pragma unroll
        for (int vv = u + 1; vv < 8; ++vv) {
            float cx = v[u][1]*v[vv][2] - v[u][2]*v[vv][1];
            float cy = v[u][2]*v[vv][0] - v[u][0]*v[vv][2];
            float cz = v[u][0]*v[vv][1] - v[u][1]*v[vv][0];
#pragma unroll
            for (int w = 0; w < 8; ++w) {
                float a = cw[2176 + p*16 + W0 + w];
                ox[W0+w] += a*cx; oy[W0+w] += a*cy; oz[W0+w] += a*cz;
            }
            ++p;
        }
    }
}

// ---------------- layer 2: 16 -> 8, single pass -----------------------------
__device__ __forceinline__ void l2_pass(
    const float (&s)[16], const float (&vx)[16], const float (&vy)[16], const float (&vz)[16],
    float (&zs)[8], float (&zx)[8], float (&zy)[8], float (&zz)[8])
{
#pragma unroll
    for (int w = 0; w < 8; ++w) { zs[w]=0.f; zx[w]=0.f; zy[w]=0.f; zz[w]=0.f; }
    {   // symmetric
        int p = 0;
#pragma unroll
        for (int u = 0; u < 16; ++u)
#pragma unroll
        for (int vv = u; vv < 16; ++vv) {
            float pp = s[u] * s[vv];
            float dd = vx[u]*vx[vv] + vy[u]*vy[vv] + vz[u]*vz[vv];
#pragma unroll
            for (int w = 0; w < 8; ++w)
                zs[w] += pp * cw[2624 + p*16 + w] + dd * cw[2624 + p*16 + 8 + w];
            ++p;
        }
    }
#pragma unroll
    for (int vv = 0; vv < 16; ++vv) {
        float tw[8];
#pragma unroll
        for (int w = 0; w < 8; ++w) tw[w] = 0.f;
#pragma unroll
        for (int u = 0; u < 16; ++u) {
            float su = s[u];
#pragma unroll
            for (int w = 0; w < 8; ++w) tw[w] += su * cw[4800 + (vv*16+u)*8 + w];
        }
#pragma unroll
        for (int w = 0; w < 8; ++w) {
            zx[w] += tw[w] * vx[vv];
            zy[w] += tw[w] * vy[vv];
            zz[w] += tw[w] * vz[vv];
        }
    }
    {   // cross
        int p = 0;
#pragma unroll
        for (int u = 0; u < 16; ++u)
#pragma unroll
        for (int vv = u + 1; vv < 16; ++vv) {
            float cx = vy[u]*vz[vv] - vz[u]*vy[vv];
            float cy = vz[u]*vx[vv] - vx[u]*vz[vv];
            float cz = vx[u]*vy[vv] - vy[u]*vx[vv];
#pragma unroll
            for (int w = 0; w < 8; ++w) {
                float a = cw[6848 + p*8 + w];
                zx[w] += a*cx; zy[w] += a*cy; zz[w] += a*cz;
            }
            ++p;
        }
    }
}

// ---------------- scalar norms ----------------
__device__ __forceinline__ void si_norm16_s(float (&ys)[16], float (&ox)[16], float (&oy)[16], float (&oz)[16])
{
    float sum = 0.f;
#pragma unroll
    for (int i = 0; i < 16; ++i) sum += ys[i];
    float m = sum * (1.f/16);
    float var = 0.f;
#pragma unroll
    for (int i = 0; i < 16; ++i) { float d = ys[i] - m; var += d*d; }
    float inv = 1.f / (sqrtf(var * (1.f/15)) + 1e-9f);
#pragma unroll
    for (int i = 0; i < 16; ++i) ys[i] *= inv;

    float n1[16]; float sn = 0.f;
#pragma unroll
    for (int i = 0; i < 16; ++i) {
        n1[i] = sqrtf(ox[i]*ox[i] + oy[i]*oy[i] + oz[i]*oz[i] + 1e-9f);
        sn += n1[i];
    }
    float mn = sn * (1.f/16);
    float vr = 0.f;
#pragma unroll
    for (int i = 0; i < 16; ++i) { float d = n1[i] - mn; vr += d*d; }
    float invv = 1.f / (sqrtf(vr * (1.f/15)) + 1e-9f);
#pragma unroll
    for (int i = 0; i < 16; ++i) { ox[i] *= invv; oy[i] *= invv; oz[i] *= invv; }
}

__device__ __forceinline__ void tv_norm16_s(float (&ys)[16], float (&ox)[16], float (&oy)[16], float (&oz)[16])
{
    float ss = 0.f;
#pragma unroll
    for (int i = 0; i < 16; ++i) ss += ys[i]*ys[i];
    float inv = 1.f / sqrtf(ss + 1e-6f);
#pragma unroll
    for (int i = 0; i < 16; ++i) ys[i] *= inv;

    float a0 = 0.f, a1 = 0.f, a2 = 0.f;
#pragma unroll
    for (int i = 0; i < 16; ++i) { a0 += ox[i]*ox[i]; a1 += oy[i]*oy[i]; a2 += oz[i]*oz[i]; }
    float nm = (sqrtf(a0+1e-6f) + sqrtf(a1+1e-6f) + sqrtf(a2+1e-6f)) * (1.f/3.f);
    float invv = 1.f / (nm + 1e-6f);
#pragma unroll
    for (int i = 0; i < 16; ++i) { ox[i] *= invv; oy[i] *= invv; oz[i] *= invv; }
}

__device__ __forceinline__ void si_norm8_s(float (&zs)[8], float (&zx)[8], float (&zy)[8], float (&zz)[8])
{
    float sum = 0.f;
#pragma unroll
    for (int i = 0; i < 8; ++i) sum += zs[i];
    float m = sum * (1.f/8);
    float var = 0.f;
#pragma unroll
    for (int i = 0; i < 8; ++i) { float d = zs[i] - m; var += d*d; }
    float inv = 1.f / (sqrtf(var * (1.f/7)) + 1e-9f);
#pragma unroll
    for (int i = 0; i < 8; ++i) zs[i] *= inv;

    float n1[8]; float sn = 0.f;
#pragma unroll
    for (int i = 0; i < 8; ++i) {
        n1[i] = sqrtf(zx[i]*zx[i] + zy[i]*zy[i] + zz[i]*zz[i] + 1e-9f);
        sn += n1[i];
    }
    float mn = sn * (1.f/8);
    float vr = 0.f;
#pragma unroll
    for (int i = 0; i < 8; ++i) { float d = n1[i] - mn; vr += d*d; }
    float invv = 1.f / (sqrtf(vr * (1.f/7)) + 1e-9f);
#pragma unroll
    for (int i = 0; i < 8; ++i) { zx[i] *= invv; zy[i] *= invv; zz[i] *= invv; }
}

__device__ __forceinline__ float fast_tanh(float x) {
    return 1.f - 2.f / (__expf(2.f * x) + 1.f);
}

// Fused kernel. No LDS; weights via __constant__ -> scalar pipe s_load.
// __launch_bounds__(256) only (R2). Chunk+fence skeleton (R4/R6).
__global__ __launch_bounds__(256) void DoubleLayer_main_kernel(
    const float* __restrict__ x,
    float* __restrict__ out)
{
    int row = blockIdx.x * 256 + threadIdx.x;
    const float4* xr = reinterpret_cast<const float4*>(x + (size_t)row * 32);
    float4 q0 = xr[0], q1 = xr[1], q2 = xr[2], q3 = xr[3];
    float4 q4 = xr[4], q5 = xr[5], q6 = xr[6], q7 = xr[7];

    float s1[8];
    s1[0] = fast_tanh(q0.x); s1[1] = fast_tanh(q0.y); s1[2] = fast_tanh(q0.z); s1[3] = fast_tanh(q0.w);
    s1[4] = fast_tanh(q1.x); s1[5] = fast_tanh(q1.y); s1[6] = fast_tanh(q1.z); s1[7] = fast_tanh(q1.w);
    float v1[8][3];
    v1[0][0]=q2.x; v1[0][1]=q2.y; v1[0][2]=q2.z;
    v1[1][0]=q2.w; v1[1][1]=q3.x; v1[1][2]=q3.y;
    v1[2][0]=q3.z; v1[2][1]=q3.w; v1[2][2]=q4.x;
    v1[3][0]=q4.y; v1[3][1]=q4.z; v1[3][2]=q4.w;
    v1[4][0]=q5.x; v1[4][1]=q5.y; v1[4][2]=q5.z;
    v1[5][0]=q5.w; v1[5][1]=q6.x; v1[5][2]=q6.y;
    v1[6][0]=q6.z; v1[6][1]=q6.w; v1[6][2]=q7.x;
    v1[7][0]=q7.y; v1[7][1]=q7.z; v1[7][2]=q7.w;

    float ys[16], ox[16], oy[16], oz[16];
    l1_chunk<0>(s1, v1, ys, ox, oy, oz);
    __builtin_amdgcn_sched_barrier(0);
    l1_chunk<8>(s1, v1, ys, ox, oy, oz);
    __builtin_amdgcn_sched_barrier(0);

    si_norm16_s(ys, ox, oy, oz);
    tv_norm16_s(ys, ox, oy, oz);
    __builtin_amdgcn_sched_barrier(0);

    float zs[8], zx[8], zy[8], zz[8];
    l2_pass(ys, ox, oy, oz, zs, zx, zy, zz);
    __builtin_amdgcn_sched_barrier(0);

    si_norm8_s(zs, zx, zy, zz);

    float o[32];
#pragma unroll
    for (int w = 0; w < 8; ++w) o[w] = 1.f / (1.f + __expf(-zs[w]));
#pragma unroll
    for (int w = 0; w < 8; ++w) {
        o[8+3*w+0] = zx[w]; o[8+3*w+1] = zy[w]; o[8+3*w+2] = zz[w];
    }
    float4* orow = reinterpret_cast<float4*>(out + (size_t)row * 32);
#pragma unroll
    for (int i = 0; i < 8; ++i) orow[i] = make_float4(o[4*i+0], o[4*i+1], o[4*i+2], o[4*i+3]);
}

extern "C" void kernel_launch(void* const* d_in, const int* in_sizes, int n_in,
                              void* d_out, int out_size, void* d_ws, size_t ws_size,
                              hipStream_t stream)
{
    const float* x = (const float*)d_in[0];
    float* ws = (float*)d_ws;
    prep_kernel<<<31, 256, 0, stream>>>(
        (const float*)d_in[1], (const float*)d_in[2], (const float*)d_in[3],
        (const float*)d_in[4], (const float*)d_in[5],
        (const float*)d_in[6], (const float*)d_in[7], (const float*)d_in[8],
        (const float*)d_in[9], (const float*)d_in[10], ws);
    hipMemcpyToSymbolAsync(HIP_SYMBOL(cw), ws, WS_TOT * sizeof(float), 0,
                           hipMemcpyDeviceToDevice, stream);
    DoubleLayer_main_kernel<<<NBROWS/256, 256, 0, stream>>>(x, (float*)d_out);
}